// Round 12
// baseline (143.397 us; speedup 1.0000x reference)
//
#include <hip/hip_runtime.h>
#include <hip/hip_bf16.h>

#define LOG2E    1.4426950408889634f
#define TWOLOG2E 2.8853900817779268f

typedef short bf16x8 __attribute__((ext_vector_type(8)));
typedef float f32x4  __attribute__((ext_vector_type(4)));
typedef unsigned short u16x8 __attribute__((ext_vector_type(8)));

static __device__ __forceinline__ float bf16_to_f(unsigned short u) {
    union { unsigned int i; float f; } v; v.i = ((unsigned int)u) << 16; return v.f;
}
static __device__ __forceinline__ unsigned short f_to_bf16_rne(float x) {
    union { float f; unsigned int i; } v; v.f = x;
    unsigned int lsb = (v.i >> 16) & 1u;
    v.i += 0x7fffu + lsb;
    return (unsigned short)(v.i >> 16);
}
static __device__ __forceinline__ float sigma_rcp(float x) {
    // rcp(1 + exp2(x)) ; x pre-scaled by 2*log2(e)
    return __builtin_amdgcn_rcpf(1.0f + __builtin_amdgcn_exp2f(x));
}

// ---------------------------------------------------------------------------
// cast_frag: f32 inputs -> split bf16 hi/lo in MFMA-fragment-linear layout.
// (unchanged since R2; verified absmax 6e-5). W pre-scaled by 2*log2(e).
// frag-record: 16-row tile f, k-tile kt, lane l -> shorts at f*12288+kt*512+l*8
// ---------------------------------------------------------------------------
__global__ __launch_bounds__(256) void cast_frag(
    const float* __restrict__ bert, const float* __restrict__ query,
    const float* __restrict__ Ww,
    unsigned short* __restrict__ Ahf, unsigned short* __restrict__ Alf,
    unsigned short* __restrict__ Whf, unsigned short* __restrict__ Wlf)
{
    const int i    = blockIdx.x * 256 + threadIdx.x;   // exact grid: 1440*256
    const int lane = i & 63;
    const float* src;
    float scale;
    unsigned short *dh, *dl;
    size_t di;
    if (i < 221184) {
        const int rest = i >> 6;
        const int kt = rest % 24, mt = rest / 24;
        const int m  = mt * 16 + (lane & 15);
        src = ((m < 2048) ? bert + (size_t)m * 768
                          : query + (size_t)(m - 2048) * 768)
              + kt * 32 + (lane >> 4) * 8;
        scale = 1.0f;
        dh = Ahf; dl = Alf; di = (size_t)i * 8;
    } else {
        const int j = i - 221184;
        const int rest = j >> 6;
        const int kt = rest % 24, nt2 = rest / 24;     // nt2 = sel*48 + nt
        const int sel = (nt2 >= 48) ? 1 : 0;
        const int n   = (nt2 - sel * 48) * 16 + (lane & 15);
        src = Ww + (size_t)n * 1536 + sel * 768 + kt * 32 + (lane >> 4) * 8;
        scale = TWOLOG2E;
        dh = Whf; dl = Wlf; di = (size_t)j * 8;
    }
    float4 x0 = *(const float4*)src;
    float4 x1 = *(const float4*)(src + 4);
    float xs[8] = {x0.x * scale, x0.y * scale, x0.z * scale, x0.w * scale,
                   x1.x * scale, x1.y * scale, x1.z * scale, x1.w * scale};
    u16x8 h, l;
    #pragma unroll
    for (int e = 0; e < 8; ++e) {
        unsigned short hh = f_to_bf16_rne(xs[e]);
        h[e] = hh;
        l[e] = f_to_bf16_rne(xs[e] - bf16_to_f(hh));
    }
    *(u16x8*)(dh + di) = h;
    *(u16x8*)(dl + di) = l;
}

// ---------------------------------------------------------------------------
// gemm_qp: query projection only (the isq path of R11 gemm_lds).
// Grid 48 (4 mtiles x 12 ntiles). qp[256][768] = query.W_q^T*2log2e + bias.
// ---------------------------------------------------------------------------
__global__ __launch_bounds__(256) void gemm_qp(
    const unsigned short* __restrict__ Ahf, const unsigned short* __restrict__ Alf,
    const unsigned short* __restrict__ Whf, const unsigned short* __restrict__ Wlf,
    const float* __restrict__ Wb, float* __restrict__ qp)
{
    __shared__ short lds[8192];
    const int t    = threadIdx.x;
    const int w    = t >> 6;
    const int lane = t & 63;
    const int wi   = w >> 1;
    const int wj   = w & 1;
    const int lr   = lane & 15;
    const int kg   = lane >> 4;

    const int mt2q = blockIdx.x / 12;        // 0..3
    const int nt2  = blockIdx.x % 12;
    const int fmtA = (32 + mt2q) * 4;
    const int fntB = 48 + nt2 * 4;

    const unsigned short* gsrc[4];
    #pragma unroll
    for (int c = 0; c < 4; ++c) {
        const int r = w * 4 + c;
        if (r < 8) {
            const int f = r >> 1;
            gsrc[c] = ((r & 1) ? Alf : Ahf) + (size_t)(fmtA + f) * 12288 + lane * 8;
        } else {
            const int f = (r - 8) >> 1;
            gsrc[c] = ((r & 1) ? Wlf : Whf) + (size_t)(fntB + f) * 12288 + lane * 8;
        }
    }

    f32x4 acc[2][2];
    #pragma unroll
    for (int i = 0; i < 2; ++i)
        #pragma unroll
        for (int j = 0; j < 2; ++j) acc[i][j] = (f32x4){0.f, 0.f, 0.f, 0.f};

    for (int kt = 0; kt < 24; ++kt) {
        #pragma unroll
        for (int c = 0; c < 4; ++c) {
            const int r = w * 4 + c;
            __builtin_amdgcn_global_load_lds(
                (const __attribute__((address_space(1))) unsigned int*)(gsrc[c] + kt * 512),
                (__attribute__((address_space(3))) unsigned int*)&lds[r * 512],
                16, 0, 0);
        }
        __syncthreads();
        bf16x8 ah[2], al[2], bh[2], bl[2];
        #pragma unroll
        for (int ii = 0; ii < 2; ++ii) {
            const int a = 2 * wi + ii;
            ah[ii] = *(const bf16x8*)&lds[(a * 2 + 0) * 512 + lane * 8];
            al[ii] = *(const bf16x8*)&lds[(a * 2 + 1) * 512 + lane * 8];
        }
        #pragma unroll
        for (int jj = 0; jj < 2; ++jj) {
            const int bb = 2 * wj + jj;
            bh[jj] = *(const bf16x8*)&lds[4096 + (bb * 2 + 0) * 512 + lane * 8];
            bl[jj] = *(const bf16x8*)&lds[4096 + (bb * 2 + 1) * 512 + lane * 8];
        }
        #pragma unroll
        for (int ii = 0; ii < 2; ++ii)
            #pragma unroll
            for (int jj = 0; jj < 2; ++jj) {
                acc[ii][jj] = __builtin_amdgcn_mfma_f32_16x16x32_bf16(ah[ii], bh[jj], acc[ii][jj], 0, 0, 0);
                acc[ii][jj] = __builtin_amdgcn_mfma_f32_16x16x32_bf16(ah[ii], bl[jj], acc[ii][jj], 0, 0, 0);
                acc[ii][jj] = __builtin_amdgcn_mfma_f32_16x16x32_bf16(al[ii], bh[jj], acc[ii][jj], 0, 0, 0);
            }
        __syncthreads();
    }

    const int n0 = nt2 * 64 + wj * 32;
    #pragma unroll
    for (int jj = 0; jj < 2; ++jj) {
        const int col  = n0 + jj * 16 + lr;
        const float bias = Wb[col] * TWOLOG2E;
        #pragma unroll
        for (int ii = 0; ii < 2; ++ii)
            #pragma unroll
            for (int r = 0; r < 4; ++r) {
                const int row = mt2q * 64 + wi * 32 + ii * 16 + kg * 4 + r;
                qp[(size_t)row * 768 + col] = acc[ii][jj][r] + bias;
            }
    }
}

// ---------------------------------------------------------------------------
// gemm_bp_attn: bert projection tile [64k x 64l] kept in registers, fused with
// the sigma-reduction over its 64 k for all 64 q of the tile's batch.
// Phase 1 == R11 gemm_lds bert path (verified). Phase 2: stage qp slice
// [64q][64k] + v_w[64k] in LDS, per q: s[l] = sum_k vk*rcp(1+exp2(bp+qp)),
// butterfly over kg lanes, write partial plane p = kt2*2+wj (24 planes).
// Grid 384 = 32 mtiles x 12 ktiles. Eliminates bpT entirely.
// ---------------------------------------------------------------------------
__global__ __launch_bounds__(256) void gemm_bp_attn(
    const unsigned short* __restrict__ Ahf, const unsigned short* __restrict__ Alf,
    const unsigned short* __restrict__ Whf, const unsigned short* __restrict__ Wlf,
    const float* __restrict__ qp, const float* __restrict__ v_w,
    float* __restrict__ Xp)
{
    __shared__ short lds[8192];              // phase1: 16 frag records; phase2: qp slice
    __shared__ float vws[64];
    const int t    = threadIdx.x;
    const int w    = t >> 6;
    const int lane = t & 63;
    const int wi   = w >> 1;
    const int wj   = w & 1;
    const int lr   = lane & 15;
    const int kg   = lane >> 4;

    const int mt2 = blockIdx.x / 12;         // 0..31 (l tiles)
    const int kt2 = blockIdx.x % 12;         // 0..11 (k tiles)
    const int fmtA = mt2 * 4;
    const int fntB = kt2 * 4;

    const unsigned short* gsrc[4];
    #pragma unroll
    for (int c = 0; c < 4; ++c) {
        const int r = w * 4 + c;
        if (r < 8) {
            const int f = r >> 1;
            gsrc[c] = ((r & 1) ? Alf : Ahf) + (size_t)(fmtA + f) * 12288 + lane * 8;
        } else {
            const int f = (r - 8) >> 1;
            gsrc[c] = ((r & 1) ? Wlf : Whf) + (size_t)(fntB + f) * 12288 + lane * 8;
        }
    }

    f32x4 acc[2][2];                         // [ii=l-half][jj=k-half]
    #pragma unroll
    for (int i = 0; i < 2; ++i)
        #pragma unroll
        for (int j = 0; j < 2; ++j) acc[i][j] = (f32x4){0.f, 0.f, 0.f, 0.f};

    for (int kt = 0; kt < 24; ++kt) {
        #pragma unroll
        for (int c = 0; c < 4; ++c) {
            const int r = w * 4 + c;
            __builtin_amdgcn_global_load_lds(
                (const __attribute__((address_space(1))) unsigned int*)(gsrc[c] + kt * 512),
                (__attribute__((address_space(3))) unsigned int*)&lds[r * 512],
                16, 0, 0);
        }
        __syncthreads();
        bf16x8 ah[2], al[2], bh[2], bl[2];
        #pragma unroll
        for (int ii = 0; ii < 2; ++ii) {
            const int a = 2 * wi + ii;
            ah[ii] = *(const bf16x8*)&lds[(a * 2 + 0) * 512 + lane * 8];
            al[ii] = *(const bf16x8*)&lds[(a * 2 + 1) * 512 + lane * 8];
        }
        #pragma unroll
        for (int jj = 0; jj < 2; ++jj) {
            const int bb = 2 * wj + jj;
            bh[jj] = *(const bf16x8*)&lds[4096 + (bb * 2 + 0) * 512 + lane * 8];
            bl[jj] = *(const bf16x8*)&lds[4096 + (bb * 2 + 1) * 512 + lane * 8];
        }
        // swapped operands -> acc = D[k][l]
        #pragma unroll
        for (int ii = 0; ii < 2; ++ii)
            #pragma unroll
            for (int jj = 0; jj < 2; ++jj) {
                acc[ii][jj] = __builtin_amdgcn_mfma_f32_16x16x32_bf16(bh[jj], ah[ii], acc[ii][jj], 0, 0, 0);
                acc[ii][jj] = __builtin_amdgcn_mfma_f32_16x16x32_bf16(bh[jj], al[ii], acc[ii][jj], 0, 0, 0);
                acc[ii][jj] = __builtin_amdgcn_mfma_f32_16x16x32_bf16(bl[jj], ah[ii], acc[ii][jj], 0, 0, 0);
            }
        __syncthreads();
    }
    // acc[ii][jj][r] = bp[l][k]: l = mt2*64 + wi*32 + ii*16 + lr
    //                            k = kt2*64 + wj*32 + jj*16 + kg*4 + r

    // ---- phase 2: fused sigma-reduction ----
    const int b  = (mt2 * 64) >> 9;          // batch (mt2/8)
    const int k0 = kt2 * 64;
    float* qps = (float*)lds;                // [64 q][64 k] = 16 KB
    #pragma unroll
    for (int it = 0; it < 4; ++it) {
        const int idx = it * 256 + t;        // 0..1023 float4s
        const int row = idx >> 4;
        const int col = (idx & 15) * 4;
        *(float4*)&qps[row * 64 + col] =
            *(const float4*)(qp + (size_t)(b * 64 + row) * 768 + k0 + col);
    }
    if (t < 16) *(float4*)&vws[t * 4] = *(const float4*)(v_w + k0 + t * 4);
    __syncthreads();

    const int kb = wj * 32;                  // wave's k-offset in tile
    const float4 vk0 = *(const float4*)&vws[kb + kg * 4];        // jj=0
    const float4 vk1 = *(const float4*)&vws[kb + 16 + kg * 4];   // jj=1
    float* xplane = Xp + (size_t)(kt2 * 2 + wj) * 131072
                  + (size_t)(b * 64) * 512 + (mt2 & 7) * 64 + wi * 32 + lr;

    for (int q = 0; q < 64; ++q) {
        const float4 qk0 = *(const float4*)&qps[q * 64 + kb + kg * 4];
        const float4 qk1 = *(const float4*)&qps[q * 64 + kb + 16 + kg * 4];
        float s0 = 0.f, s1 = 0.f;
        #pragma unroll
        for (int r = 0; r < 4; ++r) {
            const float v0 = ((const float*)&vk0)[r];
            const float v1 = ((const float*)&vk1)[r];
            const float a0 = ((const float*)&qk0)[r];
            const float a1 = ((const float*)&qk1)[r];
            s0 = fmaf(v0, sigma_rcp(acc[0][0][r] + a0), s0);
            s0 = fmaf(v1, sigma_rcp(acc[0][1][r] + a1), s0);
            s1 = fmaf(v0, sigma_rcp(acc[1][0][r] + a0), s1);
            s1 = fmaf(v1, sigma_rcp(acc[1][1][r] + a1), s1);
        }
        // butterfly over kg lanes (xor 16, 32): every lane gets 32-k sum
        s0 += __shfl_xor(s0, 16); s0 += __shfl_xor(s0, 32);
        s1 += __shfl_xor(s1, 16); s1 += __shfl_xor(s1, 32);
        if (kg == (q & 3)) {                 // 16 lanes (lr) store row q
            xplane[(size_t)q * 512 + 0]  = s0;   // ii=0 -> l offset +0
            xplane[(size_t)q * 512 + 16] = s1;   // ii=1 -> l offset +16
        }
    }
}

// masked softmax over l (512) per (b,q) row; sums the 24 k-partial planes
__global__ __launch_bounds__(512) void softmax_mask(
    const float* __restrict__ Xp, const int* __restrict__ mask,
    float* __restrict__ out)
{
    const int bq  = blockIdx.x;
    const int b   = bq >> 6;
    const int l   = threadIdx.x;
    const int wid = l >> 6;
    __shared__ float red[8];

    const size_t idx = (size_t)bq * 512 + l;
    float v = 0.f;
    #pragma unroll
    for (int p = 0; p < 24; ++p) v += Xp[idx + (size_t)p * 131072];
    v *= -2.f;
    const bool mk = (mask[b * 512 + l] != 0);
    v = mk ? v : -1e25f;

    float m = v;
    #pragma unroll
    for (int o = 32; o; o >>= 1) m = fmaxf(m, __shfl_xor(m, o));
    if ((l & 63) == 0) red[wid] = m;
    __syncthreads();
    #pragma unroll
    for (int i = 0; i < 8; ++i) m = fmaxf(m, red[i]);

    float e = __builtin_amdgcn_exp2f((v - m) * LOG2E);
    float s = e;
    #pragma unroll
    for (int o = 32; o; o >>= 1) s += __shfl_xor(s, o);
    __syncthreads();
    if ((l & 63) == 0) red[wid] = s;
    __syncthreads();
    s = 0.f;
    #pragma unroll
    for (int i = 0; i < 8; ++i) s += red[i];

    out[idx] = e / s;
}

extern "C" void kernel_launch(void* const* d_in, const int* in_sizes, int n_in,
                              void* d_out, int out_size, void* d_ws, size_t ws_size,
                              hipStream_t stream)
{
    const float* bert  = (const float*)d_in[0];   // (4,512,768) f32
    const float* query = (const float*)d_in[1];   // (4,64,768)  f32
    const int*   mask  = (const int*)  d_in[2];   // (4,512)     int32 (bool)
    const float* W_w   = (const float*)d_in[3];   // (768,1536)  f32
    const float* W_b   = (const float*)d_in[4];   // (768,)      f32
    const float* v_w   = (const float*)d_in[5];   // (1,768)     f32
    const float* v_b   = (const float*)d_in[6];   // (1,) unused (softmax shift-invariant)
    (void)v_b;

    float* qp = (float*)d_ws;                      // [256][768] f32
    float* Xp = qp + (size_t)256 * 768;            // [24][256][512] f32 partials
    unsigned short* Ahf = (unsigned short*)(Xp + (size_t)24 * 256 * 512);
    unsigned short* Alf = Ahf + (size_t)2304 * 768;
    unsigned short* Whf = Alf + (size_t)2304 * 768;
    unsigned short* Wlf = Whf + (size_t)1536 * 768;
    float* out = (float*)d_out;                    // (4,64,512) f32

    cast_frag<<<1440, 256, 0, stream>>>(bert, query, W_w, Ahf, Alf, Whf, Wlf);
    gemm_qp<<<48, 256, 0, stream>>>(Ahf, Alf, Whf, Wlf, W_b, qp);
    gemm_bp_attn<<<384, 256, 0, stream>>>(Ahf, Alf, Whf, Wlf, qp, v_w, Xp);
    softmax_mask<<<dim3(256), 512, 0, stream>>>(Xp, mask, out);
}